// Round 4
// baseline (546.588 us; speedup 1.0000x reference)
//
#include <hip/hip_runtime.h>
#include <math.h>

#define NN 102400
#define FD 128
#define KC 16
#define BG 64
#define NPG 1600
#define NE 3276800
#define HB 512           // level-1 hist/scatter blocks
#define EH (NE / HB)     // 6400 edges per block
#define BINS 256         // (graph, row-quarter): bin = src/400
#define RPB 400          // rows per bin
#define ZTOT (16384 + 16384 + 131072 + 8 + 8)   // u32s zeroed by k_s

__device__ __forceinline__ void glob_addf(float* p, float v) {
  unsafeAtomicAdd(p, v);
}
__device__ __forceinline__ unsigned f2bf(float f) {
  unsigned u = __float_as_uint(f);
  u += 0x7FFFu + ((u >> 16) & 1u);
  return (u >> 16) & 0xFFFFu;
}
__device__ __forceinline__ float bf2f(unsigned h) {
  return __uint_as_float(h << 16);
}

// -------------------- k_s: softmax^2(x@W+b) + zero accumulators --------------------
__global__ __launch_bounds__(256) void k_s(const float* __restrict__ x,
    const float* __restrict__ W, const float* __restrict__ bb,
    float* __restrict__ s, unsigned* __restrict__ zbase) {
  const int t = threadIdx.x;
  const int n = blockIdx.x * 256 + t;
  for (int i = n; i < ZTOT; i += NN) zbase[i] = 0u;
  float acc[KC];
#pragma unroll
  for (int k = 0; k < KC; ++k) acc[k] = bb[k];
  const float4* xr = (const float4*)(x + (size_t)n * FD);
#pragma unroll 4
  for (int c = 0; c < FD / 4; ++c) {
    float4 v = xr[c];
    const float* wr = W + c * 4 * KC;   // wave-uniform -> scalar loads
#pragma unroll
    for (int k = 0; k < KC; ++k)
      acc[k] += v.x * wr[k] + v.y * wr[KC + k] + v.z * wr[2 * KC + k] + v.w * wr[3 * KC + k];
  }
#pragma unroll
  for (int r = 0; r < 2; ++r) {
    float m = acc[0];
#pragma unroll
    for (int k = 1; k < KC; ++k) m = fmaxf(m, acc[k]);
    float sum = 0.f;
#pragma unroll
    for (int k = 0; k < KC; ++k) { acc[k] = expf(acc[k] - m); sum += acc[k]; }
    float inv = 1.f / sum;
#pragma unroll
    for (int k = 0; k < KC; ++k) acc[k] *= inv;
  }
  float4* so = (float4*)(s + (size_t)n * KC);
  so[0] = make_float4(acc[0], acc[1], acc[2], acc[3]);
  so[1] = make_float4(acc[4], acc[5], acc[6], acc[7]);
  so[2] = make_float4(acc[8], acc[9], acc[10], acc[11]);
  so[3] = make_float4(acc[12], acc[13], acc[14], acc[15]);
}

// -------------------- level-1: per-(bin,block) histogram, 256 bins --------------------
__global__ __launch_bounds__(256) void k_hist(const int* __restrict__ esrc,
    unsigned* __restrict__ blkhist) {
  __shared__ unsigned h[BINS];
  const int t = threadIdx.x, b = blockIdx.x;
  h[t] = 0u;
  __syncthreads();
  const int e0 = b * EH;
  for (int i = t; i < EH; i += 256) {
    unsigned bin = (unsigned)esrc[e0 + i] / (unsigned)RPB;
    atomicAdd(&h[bin], 1u);           // ds_add, no-return
  }
  __syncthreads();
  blkhist[t * HB + b] = h[t];
}

// ------------- level-1 scan A (256 bins x HB entries) + zero Mg tail -------------
__global__ __launch_bounds__(512) void k_scan_a(unsigned* __restrict__ blkhist,
    unsigned* __restrict__ gtot, unsigned* __restrict__ mgz) {
  __shared__ unsigned wsum[8];
  const int t = threadIdx.x, bin = blockIdx.x;
  const int lane = t & 63;
  // zero the Mg region beyond blkhist (Mg aliases blkhist; first 131072 u32s
  // are zeroed per-column by k_scatter1 after it consumes them)
  {
    const unsigned idx = (unsigned)bin * 512u + (unsigned)t;
    for (unsigned i = 131072u + idx; i < 1638400u; i += 131072u) mgz[i] = 0u;
  }
  unsigned v = blkhist[bin * HB + t];
  unsigned inc = v;
#pragma unroll
  for (int o = 1; o < 64; o <<= 1) {
    unsigned nb = __shfl_up(inc, o, 64);
    if (lane >= o) inc += nb;
  }
  if (lane == 63) wsum[t >> 6] = inc;
  __syncthreads();
  if (t == 0) {
    unsigned run = 0;
#pragma unroll
    for (int i = 0; i < 8; ++i) { unsigned c = wsum[i]; wsum[i] = run; run += c; }
    gtot[bin] = run;
  }
  __syncthreads();
  blkhist[bin * HB + t] = inc - v + wsum[t >> 6];
}

// -------------------- level-1 scan B: one-wave scan of 256 bin totals ---------------
__global__ __launch_bounds__(64) void k_scan_b(const unsigned* __restrict__ gtot,
    unsigned* __restrict__ gbase) {
  const int t = threadIdx.x;   // 64 lanes x 4 bins
  unsigned v0 = gtot[t * 4], v1 = gtot[t * 4 + 1];
  unsigned v2 = gtot[t * 4 + 2], v3 = gtot[t * 4 + 3];
  unsigned sum = v0 + v1 + v2 + v3;
  unsigned inc = sum;
#pragma unroll
  for (int o = 1; o < 64; o <<= 1) {
    unsigned nb = __shfl_up(inc, o, 64);
    if (t >= o) inc += nb;
  }
  unsigned ex = inc - sum;
  gbase[t * 4] = ex;
  gbase[t * 4 + 1] = ex + v0;
  gbase[t * 4 + 2] = ex + v0 + v1;
  gbase[t * 4 + 3] = ex + v0 + v1 + v2;
  if (t == 63) gbase[BINS] = inc;   // == NE
}

// ------------- level-1 scatter: group edges by (graph,row-quarter) bin --------------
__global__ __launch_bounds__(256) void k_scatter1(const float* __restrict__ ew,
    const int* __restrict__ esrc, const int* __restrict__ edst,
    unsigned* __restrict__ blkhist, const unsigned* __restrict__ gbase,
    unsigned short* __restrict__ skey, unsigned* __restrict__ pay) {
  __shared__ unsigned h[BINS];
  __shared__ unsigned off[BINS];
  const int t = threadIdx.x, b = blockIdx.x;
  h[t] = 0u;
  off[t] = gbase[t] + blkhist[t * HB + b];
  blkhist[t * HB + b] = 0u;          // zero own column: Mg aliases this region
  __syncthreads();
  const int e0 = b * EH;
  for (int i = t; i < EH; i += 256) {
    int e = e0 + i;
    int s0 = esrc[e], d0 = edst[e];
    float w = ew[e];
    unsigned bin = (unsigned)s0 / (unsigned)RPB;
    unsigned g = bin >> 2;
    unsigned r = atomicAdd(&h[bin], 1u);
    unsigned pos = off[bin] + r;
    skey[pos] = (unsigned short)((unsigned)s0 - bin * RPB);       // row-in-quarter
    pay[pos] = (((unsigned)d0 - g * NPG) << 16) | f2bf(w);        // dst-in-graph | w
  }
}

// ---- k_msc2: M[i,:] += w*s[dst,:] via LDS atomics over 400-row bins; den folded ----
// 16-lane group per edge: one 64B-coalesced gather of s[dst,0:16], one ds_add per
// lane into Ml[row][l] (stride-17 pad). 4 sub-slices/bin -> 1024 blocks, 4/CU.
__global__ __launch_bounds__(256, 4) void k_msc2(const float* __restrict__ s,
    const unsigned short* __restrict__ skey, const unsigned* __restrict__ pay,
    const unsigned* __restrict__ gbase, float* __restrict__ Mg,
    float* __restrict__ den) {
  __shared__ float Ml[RPB * 17];
  __shared__ float scr[4];
  const int t = threadIdx.x;
  const int bin = blockIdx.x & 255;     // sub-slices of a bin share an XCD
  const int sub = blockIdx.x >> 8;      // 0..3
  const int l = t & 15;
  const int gi = sub * 16 + (t >> 4);   // 0..63 group id within bin
  for (int i = t; i < RPB * 17; i += 256) Ml[i] = 0.f;
  __syncthreads();
  const unsigned gb = gbase[bin], ge = gbase[bin + 1];
  const int g = bin >> 2;
  const float* sG = s + (size_t)g * NPG * KC;
  float dacc = 0.f;
  unsigned e = gb + gi;
  for (; e + 192 < ge; e += 256) {      // 4 independent chains per lane
    unsigned pk0 = pay[e],       pk1 = pay[e + 64];
    unsigned pk2 = pay[e + 128], pk3 = pay[e + 192];
    unsigned sk0 = skey[e],       sk1 = skey[e + 64];
    unsigned sk2 = skey[e + 128], sk3 = skey[e + 192];
    float sv0 = sG[(pk0 >> 16) * KC + l];
    float sv1 = sG[(pk1 >> 16) * KC + l];
    float sv2 = sG[(pk2 >> 16) * KC + l];
    float sv3 = sG[(pk3 >> 16) * KC + l];
    float t0 = bf2f(pk0 & 0xFFFFu) * sv0;
    float t1 = bf2f(pk1 & 0xFFFFu) * sv1;
    float t2 = bf2f(pk2 & 0xFFFFu) * sv2;
    float t3 = bf2f(pk3 & 0xFFFFu) * sv3;
    dacc = fmaf(t0, sv0, dacc);
    dacc = fmaf(t1, sv1, dacc);
    dacc = fmaf(t2, sv2, dacc);
    dacc = fmaf(t3, sv3, dacc);
    atomicAdd(&Ml[sk0 * 17 + l], t0);   // ds_add_f32, no-return
    atomicAdd(&Ml[sk1 * 17 + l], t1);
    atomicAdd(&Ml[sk2 * 17 + l], t2);
    atomicAdd(&Ml[sk3 * 17 + l], t3);
  }
  for (; e < ge; e += 64) {
    unsigned pk0 = pay[e];
    unsigned sk0 = skey[e];
    float sv0 = sG[(pk0 >> 16) * KC + l];
    float t0 = bf2f(pk0 & 0xFFFFu) * sv0;
    dacc = fmaf(t0, sv0, dacc);
    atomicAdd(&Ml[sk0 * 17 + l], t0);
  }
  __syncthreads();
  // merge this block's partial into Mg (coalesced f32 atomics)
  float* Mq = Mg + (size_t)bin * RPB * KC;
  for (int i = t; i < RPB * KC; i += 256)
    glob_addf(Mq + i, Ml[(i >> 4) * 17 + (i & 15)]);
#pragma unroll
  for (int o = 32; o > 0; o >>= 1) dacc += __shfl_down(dacc, o, 64);
  if ((t & 63) == 0) scr[t >> 6] = dacc;
  __syncthreads();
  if (t == 0) glob_addf(den, scr[0] + scr[1] + scr[2] + scr[3]);
}

// ---- k_mid: CC = S^T S, out_x = S^T X, out_adj = S^T M (fused dense contraction) ----
__global__ __launch_bounds__(256, 8) void k_mid(const float* __restrict__ s,
    const float* __restrict__ x, const float* __restrict__ Mg,
    float* __restrict__ cc_raw, float* __restrict__ outx_raw,
    float* __restrict__ adj_raw) {
  __shared__ float st[100 * KC];
  __shared__ float mt[100 * KC];
  const int t = threadIdx.x;
  const int g = blockIdx.x >> 4, sub = blockIdx.x & 15;
  const int n0 = g * NPG + sub * 100;
  const int j = t & 127, h = t >> 7;
  const int kc = t >> 4, lc = t & 15;
  for (int u = t; u < 100 * KC; u += 256) {
    st[u] = s[(size_t)n0 * KC + u];
    mt[u] = Mg[(size_t)n0 * KC + u];
  }
  __syncthreads();
  float accX[8] = {0.f, 0.f, 0.f, 0.f, 0.f, 0.f, 0.f, 0.f};
  float accC = 0.f, accA = 0.f;
  for (int i = 0; i < 100; ++i) {
    const float xv = x[(size_t)(n0 + i) * FD + j];
    const float* si = st + i * KC;
#pragma unroll
    for (int kk = 0; kk < 8; ++kk) accX[kk] = fmaf(si[h * 8 + kk], xv, accX[kk]);
    accC = fmaf(si[kc], si[lc], accC);
    accA = fmaf(si[kc], mt[i * KC + lc], accA);
  }
#pragma unroll
  for (int kk = 0; kk < 8; ++kk)
    glob_addf(outx_raw + g * 2048 + (h * 8 + kk) * 128 + j, accX[kk]);
  glob_addf(cc_raw + g * 256 + t, accC);
  glob_addf(adj_raw + g * 256 + t, accA);
}

// -------------------- k_post: normalize adj, trace, ortho, SELU --------------------
__device__ __forceinline__ float bred(float v, float* scr) {
#pragma unroll
  for (int o = 32; o > 0; o >>= 1) v += __shfl_down(v, o, 64);
  __syncthreads();
  if ((threadIdx.x & 63) == 0) scr[threadIdx.x >> 6] = v;
  __syncthreads();
  return scr[0] + scr[1] + scr[2] + scr[3];
}

__global__ __launch_bounds__(256) void k_post(const float* __restrict__ adj_raw,
    const float* __restrict__ cc_raw, const float* __restrict__ outx_raw,
    float* __restrict__ out, float* __restrict__ scal, unsigned* __restrict__ done) {
  const int b = blockIdx.x, t = threadIdx.x;
  const int k = t >> 4, l = t & 15;
  __shared__ float m[16 * 17];
  __shared__ float dk[16];
  __shared__ float scr[4];
  const float raw = adj_raw[b * 256 + t];
  const float masked = (k == l) ? 0.f : raw;
  m[k * 17 + l] = masked;
  __syncthreads();
  if (t < 16) {
    float rs = 0.f;
#pragma unroll
    for (int ll = 0; ll < 16; ++ll) rs += m[t * 17 + ll];
    dk[t] = sqrtf(rs) + 1e-12f;
  }
  __syncthreads();
  out[131072 + b * 256 + t] = masked / (dk[k] * dk[l]);
  float tr = bred((k == l) ? raw : 0.f, scr);
  if (t == 0) glob_addf(scal + 1, tr);
  const float c = cc_raw[b * 256 + t];
  float n2 = bred(c * c, scr);
  float diff = c / sqrtf(n2) - ((k == l) ? 0.25f : 0.f);
  float d2 = bred(diff * diff, scr);
  if (t == 0) glob_addf(scal + 2, sqrtf(d2));
  for (int idx = b * 256 + t; idx < 131072; idx += 16384) {
    float xv = outx_raw[idx];
    out[idx] = xv > 0.f ? 1.0507009873554805f * xv
                        : 1.0507009873554805f * 1.6732632423543772f * expm1f(xv);
  }
  __syncthreads();
  if (t == 0) {
    __threadfence();
    unsigned v = __hip_atomic_fetch_add(done, 1u, __ATOMIC_ACQ_REL,
                                        __HIP_MEMORY_SCOPE_AGENT);
    if (v == 63u) {   // last block: all contributions visible
      float den   = __hip_atomic_load(scal + 0, __ATOMIC_RELAXED, __HIP_MEMORY_SCOPE_AGENT);
      float num   = __hip_atomic_load(scal + 1, __ATOMIC_RELAXED, __HIP_MEMORY_SCOPE_AGENT);
      float ortho = __hip_atomic_load(scal + 2, __ATOMIC_RELAXED, __HIP_MEMORY_SCOPE_AGENT);
      out[147456] = -num / den;
      out[147457] = ortho * (1.f / 64.f);
    }
  }
}

// -------------------- launch --------------------
extern "C" void kernel_launch(void* const* d_in, const int* in_sizes, int n_in,
                              void* d_out, int out_size, void* d_ws, size_t ws_size,
                              hipStream_t stream) {
  const float* x  = (const float*)d_in[0];
  const float* W  = (const float*)d_in[1];
  const float* bb = (const float*)d_in[2];
  const float* ew = (const float*)d_in[3];
  const int* esrc = (const int*)d_in[4];
  const int* edst = (const int*)d_in[5];
  float* out = (float*)d_out;
  float* ws = (float*)d_ws;

  float* s_buf   = ws;                                    // 1,638,400 f
  float* adj_raw = s_buf + (size_t)NN * KC;               // 16,384 f   <- zero region start
  float* cc_raw  = adj_raw + 16384;                       // 16,384 f
  float* outx    = cc_raw + 16384;                        // 131,072 f
  float* scal    = outx + 131072;                         // 8 f: [0]=den [1]=num [2]=ortho
  unsigned* done = (unsigned*)(scal + 8);                 // 8 u        <- zero region end
  unsigned* gtot = done + 8;                              // 256 u (written by scan_a)
  unsigned* gbase = gtot + BINS;                          // 264 u (257 used)
  float* Mg      = (float*)(gbase + 264);                 // 1,638,400 f; ALIASES blkhist
  unsigned* blkhist = (unsigned*)Mg;                      // 256*512 u = first 512KB of Mg
  unsigned short* skey = (unsigned short*)(Mg + (size_t)NN * KC);  // NE u16 (row-in-quarter)
  unsigned* pay = (unsigned*)(skey + NE);                 // NE u32 (dst-in-graph<<16 | bf16 w)
  // total ~= 33.43 MB (< 33.56 MB used successfully in R2)

  k_s<<<NN / 256, 256, 0, stream>>>(x, W, bb, s_buf, (unsigned*)adj_raw);
  k_hist<<<HB, 256, 0, stream>>>(esrc, blkhist);
  k_scan_a<<<BINS, 512, 0, stream>>>(blkhist, gtot, (unsigned*)Mg);
  k_scan_b<<<1, 64, 0, stream>>>(gtot, gbase);
  k_scatter1<<<HB, 256, 0, stream>>>(ew, esrc, edst, blkhist, gbase, skey, pay);
  k_msc2<<<BINS * 4, 256, 0, stream>>>(s_buf, skey, pay, gbase, Mg, scal);
  k_mid<<<BG * 16, 256, 0, stream>>>(s_buf, x, Mg, cc_raw, outx, adj_raw);
  k_post<<<64, 256, 0, stream>>>(adj_raw, cc_raw, outx, out, scal, done);
}